// Round 1
// baseline (13336.348 us; speedup 1.0000x reference)
//
#include <hip/hip_runtime.h>
#include <math.h>

// Problem constants
#define TX 64
#define BN 64
#define TY 32
#define EE 256
#define HH 512
#define H3 1536
#define KYV 32000

__device__ __forceinline__ float4 ldf4(const float* p) { return *(const float4*)p; }
__device__ __forceinline__ float sigf(float x) { return 1.f / (1.f + expf(-x)); }

// ---------------------------------------------------------------------------
// Generic NT GEMM: C[M x N] = A[M x K] * B[N x K]^T (+bias), optional A row gather.
// Tiles 64x64, K-tile 32, LDS k-major for float4 micro-reads.
// Requires M,N % 64 == 0, K % 32 == 0.
// ---------------------------------------------------------------------------
__global__ __launch_bounds__(256) void gemm_nt_kernel(
    const float* __restrict__ Abase, const int* __restrict__ gather, int lda,
    const float* __restrict__ Bbase, int ldb, int bofs,
    const float* __restrict__ bias, float* __restrict__ C, int ldc, int K)
{
    __shared__ float As[32][68];
    __shared__ float Bs[32][68];
    const int tid = threadIdx.x;
    const int n0 = blockIdx.x * 64;
    const int m0 = blockIdx.y * 64;
    const int tx = tid & 15, ty = tid >> 4;
    const int li = tid >> 2, lk = (tid & 3) * 8;
    float acc[4][4] = {};
    const float* arow = gather ? (Abase + (size_t)gather[m0 + li] * lda)
                               : (Abase + (size_t)(m0 + li) * lda);
    const float* brow = Bbase + (size_t)(n0 + li) * ldb + bofs;
    for (int kt = 0; kt < K; kt += 32) {
        float4 a0 = ldf4(arow + kt + lk);
        float4 a1 = ldf4(arow + kt + lk + 4);
        float4 b0 = ldf4(brow + kt + lk);
        float4 b1 = ldf4(brow + kt + lk + 4);
        __syncthreads();
        As[lk+0][li]=a0.x; As[lk+1][li]=a0.y; As[lk+2][li]=a0.z; As[lk+3][li]=a0.w;
        As[lk+4][li]=a1.x; As[lk+5][li]=a1.y; As[lk+6][li]=a1.z; As[lk+7][li]=a1.w;
        Bs[lk+0][li]=b0.x; Bs[lk+1][li]=b0.y; Bs[lk+2][li]=b0.z; Bs[lk+3][li]=b0.w;
        Bs[lk+4][li]=b1.x; Bs[lk+5][li]=b1.y; Bs[lk+6][li]=b1.z; Bs[lk+7][li]=b1.w;
        __syncthreads();
        #pragma unroll
        for (int k = 0; k < 32; ++k) {
            float4 av = *(const float4*)&As[k][ty*4];
            float4 bv = *(const float4*)&Bs[k][tx*4];
            acc[0][0] += av.x*bv.x; acc[0][1] += av.x*bv.y; acc[0][2] += av.x*bv.z; acc[0][3] += av.x*bv.w;
            acc[1][0] += av.y*bv.x; acc[1][1] += av.y*bv.y; acc[1][2] += av.y*bv.z; acc[1][3] += av.y*bv.w;
            acc[2][0] += av.z*bv.x; acc[2][1] += av.z*bv.y; acc[2][2] += av.z*bv.z; acc[2][3] += av.z*bv.w;
            acc[3][0] += av.w*bv.x; acc[3][1] += av.w*bv.y; acc[3][2] += av.w*bv.z; acc[3][3] += av.w*bv.w;
        }
    }
    #pragma unroll
    for (int ii = 0; ii < 4; ++ii) {
        int r = m0 + ty*4 + ii;
        #pragma unroll
        for (int jj = 0; jj < 4; ++jj) {
            int c = n0 + tx*4 + jj;
            float v = acc[ii][jj];
            if (bias) v += bias[c];
            C[(size_t)r*ldc + c] = v;
        }
    }
}

// ---------------------------------------------------------------------------
// Encoder recurrent step: fwd processes t, bwd processes (63-t). Grid = 256
// blocks: blocks [0,128) fwd, [128,256) bwd. Each block: 8 h-columns x 32 batch.
// gi (input part) precomputed in GI_*. Writes new h and enc_output slot.
// ---------------------------------------------------------------------------
__global__ __launch_bounds__(256) void enc_step_kernel(
    const float* __restrict__ GI_f, const float* __restrict__ GI_b,
    const float* __restrict__ Whh_f, const float* __restrict__ bhh_f,
    const float* __restrict__ Whh_b, const float* __restrict__ bhh_b,
    const float* __restrict__ hf_in, float* __restrict__ hf_out,
    const float* __restrict__ hb_in, float* __restrict__ hb_out,
    float* __restrict__ enc_out, int t)
{
    const int blk = blockIdx.x;
    const int dir = blk >> 7;             // 0 fwd, 1 bwd
    const int r = blk & 127;
    const int cg = r >> 1;                // 0..63 column group (8 cols)
    const int bh = r & 1;
    const int sub = threadIdx.x >> 5;     // 0..7
    const int b = bh*32 + (threadIdx.x & 31);
    const int col = cg*8 + sub;

    const float* GI = dir ? GI_b : GI_f;
    const float* W  = dir ? Whh_b : Whh_f;
    const float* bh_v = dir ? bhh_b : bhh_f;
    const float* hin  = dir ? hb_in : hf_in;
    float* hout = dir ? hb_out : hf_out;
    const int tstep = dir ? (TX-1-t) : t;

    const float* hrow = hin + b*HH;
    const float* wr = W + (size_t)col*HH;
    const float* wz = W + (size_t)(HH + col)*HH;
    const float* wn = W + (size_t)(2*HH + col)*HH;
    float ar = 0.f, az = 0.f, an = 0.f;
    for (int k = 0; k < HH; k += 4) {
        float4 hv = ldf4(hrow + k);
        float4 A = ldf4(wr + k), Z = ldf4(wz + k), N = ldf4(wn + k);
        ar += hv.x*A.x + hv.y*A.y + hv.z*A.z + hv.w*A.w;
        az += hv.x*Z.x + hv.y*Z.y + hv.z*Z.z + hv.w*Z.w;
        an += hv.x*N.x + hv.y*N.y + hv.z*N.z + hv.w*N.w;
    }
    size_t gbase = ((size_t)tstep*BN + b) * H3;
    float ir = GI[gbase + col];
    float iz = GI[gbase + HH + col];
    float inn = GI[gbase + 2*HH + col];
    float rr = sigf(ir + ar + bh_v[col]);
    float zz = sigf(iz + az + bh_v[HH + col]);
    float nn = tanhf(inn + rr*(an + bh_v[2*HH + col]));
    float hold = hrow[col];
    float h2 = (1.f - zz)*nn + zz*hold;
    hout[b*HH + col] = h2;
    enc_out[((size_t)tstep*BN + b)*(2*HH) + dir*HH + col] = h2;
}

// ---------------------------------------------------------------------------
// Decoder init: hidden = tanh(h_b_final @ W_init.T + b_init); tok = 1
// ---------------------------------------------------------------------------
__global__ __launch_bounds__(256) void dec_init_kernel(
    const float* __restrict__ hbf, const float* __restrict__ Wi,
    const float* __restrict__ bi, float* __restrict__ hdec, int* __restrict__ tok)
{
    const int b = blockIdx.x, tid = threadIdx.x;
    const float* hr = hbf + b*HH;
    for (int n = tid; n < HH; n += 256) {
        float acc = bi[n];
        const float* w = Wi + (size_t)n*HH;
        for (int k = 0; k < HH; k += 4) {
            float4 hv = ldf4(hr + k), wv = ldf4(w + k);
            acc += hv.x*wv.x + hv.y*wv.y + hv.z*wv.z + hv.w*wv.w;
        }
        hdec[b*HH + n] = tanhf(acc);
    }
    if (b == 0 && tid < 64) tok[tid] = 1;
}

// ---------------------------------------------------------------------------
// Attention + context, one block per batch element.
// q = h@Wa1[:, :512].T + ba1 ; s_t = Wa2 . tanh(q + P_enc[t,b]) + ba2
// w = softmax_t(s) ; context = sum_t w_t * enc_out[t,b,:]
// ---------------------------------------------------------------------------
__global__ __launch_bounds__(256) void attn_kernel(
    const float* __restrict__ h, const float* __restrict__ P,
    const float* __restrict__ enc, const float* __restrict__ Wa1,
    const float* __restrict__ ba1, const float* __restrict__ Wa2,
    const float* __restrict__ ba2, float* __restrict__ ctx)
{
    __shared__ float hs[HH];
    __shared__ float qs[HH];
    __shared__ float ss[TX];
    __shared__ float ww[TX];
    const int b = blockIdx.x, tid = threadIdx.x;
    hs[tid] = h[b*HH + tid];
    hs[tid + 256] = h[b*HH + 256 + tid];
    __syncthreads();
    for (int n = tid; n < HH; n += 256) {
        float acc = ba1[n];
        const float* w = Wa1 + (size_t)n*H3;   // first 512 cols = h part
        for (int k = 0; k < HH; k += 4) {
            float4 wv = ldf4(w + k);
            acc += hs[k]*wv.x + hs[k+1]*wv.y + hs[k+2]*wv.z + hs[k+3]*wv.w;
        }
        qs[n] = acc;
    }
    __syncthreads();
    {
        const int t = tid >> 2, part = tid & 3;
        const float* p = P + ((size_t)t*BN + b)*HH + part*128;
        const float* w2 = Wa2 + part*128;
        const float* q = qs + part*128;
        float acc = 0.f;
        for (int k = 0; k < 128; k += 4) {
            float4 pv = ldf4(p + k), wv = ldf4(w2 + k);
            acc += wv.x*tanhf(q[k+0] + pv.x);
            acc += wv.y*tanhf(q[k+1] + pv.y);
            acc += wv.z*tanhf(q[k+2] + pv.z);
            acc += wv.w*tanhf(q[k+3] + pv.w);
        }
        acc += __shfl_xor(acc, 1);
        acc += __shfl_xor(acc, 2);
        if (part == 0) ss[t] = acc + ba2[0];
    }
    __syncthreads();
    if (tid < 64) {
        float v = ss[tid];
        float m = v;
        for (int off = 32; off; off >>= 1) m = fmaxf(m, __shfl_xor(m, off));
        float e = expf(v - m);
        float sm = e;
        for (int off = 32; off; off >>= 1) sm += __shfl_xor(sm, off);
        ww[tid] = e / sm;
    }
    __syncthreads();
    for (int c = tid; c < 2*HH; c += 256) {
        float acc = 0.f;
        #pragma unroll 4
        for (int t2 = 0; t2 < TX; ++t2)
            acc += ww[t2] * enc[((size_t)t2*BN + b)*(2*HH) + c];
        ctx[b*(2*HH) + c] = acc;
    }
}

// ---------------------------------------------------------------------------
// Decoder GRU step. x = [dec_emb[tok] (256) | context (1024)], K_ih=1280, K_hh=512.
// Grid 128 blocks: 4 cols x 64 batch each.
// ---------------------------------------------------------------------------
__global__ __launch_bounds__(256) void dec_gru_kernel(
    const float* __restrict__ demb, const int* __restrict__ tok,
    const float* __restrict__ ctx, const float* __restrict__ h,
    const float* __restrict__ Wih, const float* __restrict__ Whh,
    const float* __restrict__ bih, const float* __restrict__ bhh,
    float* __restrict__ hout)
{
    const int col = blockIdx.x*4 + (threadIdx.x >> 6);
    const int b = threadIdx.x & 63;
    const float* emb = demb + (size_t)tok[b]*EE;
    const float* cr = ctx + b*(2*HH);
    const float* hr = h + b*HH;
    const float* wri = Wih + (size_t)col*1280;
    const float* wzi = Wih + (size_t)(HH + col)*1280;
    const float* wni = Wih + (size_t)(2*HH + col)*1280;
    float ir = 0.f, iz = 0.f, inn = 0.f;
    for (int k = 0; k < EE; k += 4) {
        float4 e = ldf4(emb + k);
        float4 A = ldf4(wri + k), Z = ldf4(wzi + k), N = ldf4(wni + k);
        ir  += e.x*A.x + e.y*A.y + e.z*A.z + e.w*A.w;
        iz  += e.x*Z.x + e.y*Z.y + e.z*Z.z + e.w*Z.w;
        inn += e.x*N.x + e.y*N.y + e.z*N.z + e.w*N.w;
    }
    for (int k = 0; k < 2*HH; k += 4) {
        float4 c = ldf4(cr + k);
        float4 A = ldf4(wri + EE + k), Z = ldf4(wzi + EE + k), N = ldf4(wni + EE + k);
        ir  += c.x*A.x + c.y*A.y + c.z*A.z + c.w*A.w;
        iz  += c.x*Z.x + c.y*Z.y + c.z*Z.z + c.w*Z.w;
        inn += c.x*N.x + c.y*N.y + c.z*N.z + c.w*N.w;
    }
    const float* wrh = Whh + (size_t)col*HH;
    const float* wzh = Whh + (size_t)(HH + col)*HH;
    const float* wnh = Whh + (size_t)(2*HH + col)*HH;
    float hrr = 0.f, hzz = 0.f, hnn = 0.f;
    for (int k = 0; k < HH; k += 4) {
        float4 hv = ldf4(hr + k);
        float4 A = ldf4(wrh + k), Z = ldf4(wzh + k), N = ldf4(wnh + k);
        hrr += hv.x*A.x + hv.y*A.y + hv.z*A.z + hv.w*A.w;
        hzz += hv.x*Z.x + hv.y*Z.y + hv.z*Z.z + hv.w*Z.w;
        hnn += hv.x*N.x + hv.y*N.y + hv.z*N.z + hv.w*N.w;
    }
    float rr = sigf(ir + bih[col] + hrr + bhh[col]);
    float zz = sigf(iz + bih[HH + col] + hzz + bhh[HH + col]);
    float nn = tanhf(inn + bih[2*HH + col] + rr*(hnn + bhh[2*HH + col]));
    float hv0 = hr[col];
    hout[b*HH + col] = (1.f - zz)*nn + zz*hv0;
}

// ---------------------------------------------------------------------------
// Logits GEMM: out[b, k] = [h2|ctx][b,:] . W_lsm[k,:] + b_lsm[k].  M=64 fixed,
// N tiles of 64 (grid 500), K=1536. Raw logits written to d_out slot.
// ---------------------------------------------------------------------------
__global__ __launch_bounds__(256) void logits_kernel(
    const float* __restrict__ h2, const float* __restrict__ ctx,
    const float* __restrict__ Wlsm, const float* __restrict__ blsm,
    float* __restrict__ outrow)
{
    __shared__ float As[32][68];
    __shared__ float Bs[32][68];
    const int tid = threadIdx.x;
    const int n0 = blockIdx.x * 64;
    const int tx = tid & 15, ty = tid >> 4;
    const int li = tid >> 2, lk = (tid & 3) * 8;
    float acc[4][4] = {};
    const float* arow_h = h2 + (size_t)li*HH;
    const float* arow_c = ctx + (size_t)li*(2*HH) - HH;  // +k valid for k>=512
    const float* brow = Wlsm + (size_t)(n0 + li)*H3;
    for (int kt = 0; kt < H3; kt += 32) {
        const float* src = ((kt + lk) < HH) ? arow_h : arow_c;
        float4 a0 = ldf4(src + kt + lk);
        float4 a1 = ldf4(src + kt + lk + 4);
        float4 b0 = ldf4(brow + kt + lk);
        float4 b1 = ldf4(brow + kt + lk + 4);
        __syncthreads();
        As[lk+0][li]=a0.x; As[lk+1][li]=a0.y; As[lk+2][li]=a0.z; As[lk+3][li]=a0.w;
        As[lk+4][li]=a1.x; As[lk+5][li]=a1.y; As[lk+6][li]=a1.z; As[lk+7][li]=a1.w;
        Bs[lk+0][li]=b0.x; Bs[lk+1][li]=b0.y; Bs[lk+2][li]=b0.z; Bs[lk+3][li]=b0.w;
        Bs[lk+4][li]=b1.x; Bs[lk+5][li]=b1.y; Bs[lk+6][li]=b1.z; Bs[lk+7][li]=b1.w;
        __syncthreads();
        #pragma unroll
        for (int k = 0; k < 32; ++k) {
            float4 av = *(const float4*)&As[k][ty*4];
            float4 bv = *(const float4*)&Bs[k][tx*4];
            acc[0][0] += av.x*bv.x; acc[0][1] += av.x*bv.y; acc[0][2] += av.x*bv.z; acc[0][3] += av.x*bv.w;
            acc[1][0] += av.y*bv.x; acc[1][1] += av.y*bv.y; acc[1][2] += av.y*bv.z; acc[1][3] += av.y*bv.w;
            acc[2][0] += av.z*bv.x; acc[2][1] += av.z*bv.y; acc[2][2] += av.z*bv.z; acc[2][3] += av.z*bv.w;
            acc[3][0] += av.w*bv.x; acc[3][1] += av.w*bv.y; acc[3][2] += av.w*bv.z; acc[3][3] += av.w*bv.w;
        }
    }
    #pragma unroll
    for (int ii = 0; ii < 4; ++ii) {
        int r = ty*4 + ii;
        #pragma unroll
        for (int jj = 0; jj < 4; ++jj) {
            int c = n0 + tx*4 + jj;
            outrow[(size_t)r*KYV + c] = acc[ii][jj] + blsm[c];
        }
    }
}

// ---------------------------------------------------------------------------
// Per-row (batch) logsumexp + argmax over 32000 logits. One block per row.
// ---------------------------------------------------------------------------
__global__ __launch_bounds__(256) void lse_argmax_kernel(
    const float* __restrict__ rows, float* __restrict__ lse, int* __restrict__ tok)
{
    const int b = blockIdx.x, tid = threadIdx.x;
    const float* row = rows + (size_t)b*KYV;
    float m = -1e30f, s = 0.f; int bi = 0;
    for (int k = tid; k < KYV; k += 256) {
        float v = row[k];
        if (v > m) { s = s*expf(m - v) + 1.f; m = v; bi = k; }
        else s += expf(v - m);
    }
    for (int off = 32; off; off >>= 1) {
        float m2 = __shfl_xor(m, off);
        float s2 = __shfl_xor(s, off);
        int i2 = __shfl_xor(bi, off);
        if (m2 > m || (m2 == m && i2 < bi)) { s = s2 + s*expf(m - m2); m = m2; bi = i2; }
        else s = s + s2*expf(m2 - m);
    }
    __shared__ float ms[4], ssh[4];
    __shared__ int is_[4];
    const int wid = tid >> 6;
    if ((tid & 63) == 0) { ms[wid] = m; ssh[wid] = s; is_[wid] = bi; }
    __syncthreads();
    if (tid == 0) {
        for (int w = 1; w < 4; ++w) {
            float m2 = ms[w], s2 = ssh[w]; int i2 = is_[w];
            if (m2 > m || (m2 == m && i2 < bi)) { s = s2 + s*expf(m - m2); m = m2; bi = i2; }
            else s = s + s2*expf(m2 - m);
        }
        lse[b] = m + logf(s);
        tok[b] = bi;
    }
}

// out = logits - lse[row], in-place, float4.
__global__ __launch_bounds__(256) void sub_lse_kernel(
    float* __restrict__ rows, const float* __restrict__ lse)
{
    const size_t total4 = (size_t)BN * KYV / 4;   // 512000
    for (size_t i = blockIdx.x*blockDim.x + threadIdx.x; i < total4;
         i += (size_t)gridDim.x*blockDim.x) {
        float4 v = ((float4*)rows)[i];
        float l = lse[(i*4) / KYV];
        v.x -= l; v.y -= l; v.z -= l; v.w -= l;
        ((float4*)rows)[i] = v;
    }
}

// ---------------------------------------------------------------------------
extern "C" void kernel_launch(void* const* d_in, const int* in_sizes, int n_in,
                              void* d_out, int out_size, void* d_ws, size_t ws_size,
                              hipStream_t stream)
{
    const int*   inputs  = (const int*)  d_in[0];
    const float* enc_emb = (const float*)d_in[2];
    const float* W_ih_f  = (const float*)d_in[3];
    const float* W_hh_f  = (const float*)d_in[4];
    const float* b_ih_f  = (const float*)d_in[5];
    const float* b_hh_f  = (const float*)d_in[6];
    const float* W_ih_b  = (const float*)d_in[7];
    const float* W_hh_b  = (const float*)d_in[8];
    const float* b_ih_b  = (const float*)d_in[9];
    const float* b_hh_b  = (const float*)d_in[10];
    const float* W_init  = (const float*)d_in[11];
    const float* b_init  = (const float*)d_in[12];
    const float* dec_emb = (const float*)d_in[13];
    const float* W_ih_d  = (const float*)d_in[14];
    const float* W_hh_d  = (const float*)d_in[15];
    const float* b_ih_d  = (const float*)d_in[16];
    const float* b_hh_d  = (const float*)d_in[17];
    const float* W_lsm   = (const float*)d_in[18];
    const float* b_lsm   = (const float*)d_in[19];
    const float* W_a1    = (const float*)d_in[20];
    const float* b_a1    = (const float*)d_in[21];
    const float* W_a2    = (const float*)d_in[22];
    const float* b_a2    = (const float*)d_in[23];

    float* ws = (float*)d_ws;
    float* GI_f   = ws;                               // 4096*1536
    float* GI_b   = GI_f + (size_t)4096*1536;         // 4096*1536
    float* enc_out= GI_b + (size_t)4096*1536;         // 4096*1024
    float* P_enc  = enc_out + (size_t)4096*1024;      // 4096*512
    float* hf     = P_enc + (size_t)4096*512;         // 2 * 64*512 ping-pong
    float* hb     = hf + 2*BN*HH;
    float* hdec   = hb + 2*BN*HH;                     // 2 * 64*512
    float* ctx    = hdec + 2*BN*HH;                   // 64*1024
    float* lse    = ctx + BN*2*HH;                    // 64
    int*   tok    = (int*)(lse + BN);                 // 64

    hipMemsetAsync(hf, 0, BN*HH*sizeof(float), stream);
    hipMemsetAsync(hb, 0, BN*HH*sizeof(float), stream);

    // Input projections for both encoder directions (gathered-A GEMMs)
    dim3 g1(H3/64, (TX*BN)/64);
    gemm_nt_kernel<<<g1, 256, 0, stream>>>(enc_emb, inputs, EE, W_ih_f, EE, 0,
                                           b_ih_f, GI_f, H3, EE);
    gemm_nt_kernel<<<g1, 256, 0, stream>>>(enc_emb, inputs, EE, W_ih_b, EE, 0,
                                           b_ih_b, GI_b, H3, EE);

    // 64 recurrent steps (fwd + bwd fused per launch)
    for (int t = 0; t < TX; ++t) {
        const float* hfi = hf + (t & 1)*BN*HH;
        float*       hfo = hf + ((t + 1) & 1)*BN*HH;
        const float* hbi = hb + (t & 1)*BN*HH;
        float*       hbo = hb + ((t + 1) & 1)*BN*HH;
        enc_step_kernel<<<256, 256, 0, stream>>>(GI_f, GI_b, W_hh_f, b_hh_f,
                                                 W_hh_b, b_hh_b, hfi, hfo, hbi, hbo,
                                                 enc_out, t);
    }

    // P_enc = enc_out @ W_a1[:, 512:].T   (no bias; b_a1 folded into q)
    dim3 g2(HH/64, (TX*BN)/64);
    gemm_nt_kernel<<<g2, 256, 0, stream>>>(enc_out, nullptr, 2*HH, W_a1, H3, HH,
                                           nullptr, P_enc, HH, 2*HH);

    // hidden init (+ tok=1). Final backward state sits in hb buffer 0 (t=63 wrote (64&1)=0).
    dec_init_kernel<<<BN, 256, 0, stream>>>(hb, W_init, b_init, hdec, tok);

    float* out = (float*)d_out;
    for (int s = 0; s < TY; ++s) {
        float* h_cur = hdec + (s & 1)*BN*HH;
        float* h_nxt = hdec + ((s + 1) & 1)*BN*HH;
        attn_kernel<<<BN, 256, 0, stream>>>(h_cur, P_enc, enc_out, W_a1, b_a1,
                                            W_a2, b_a2, ctx);
        dec_gru_kernel<<<128, 256, 0, stream>>>(dec_emb, tok, ctx, h_cur,
                                                W_ih_d, W_hh_d, b_ih_d, b_hh_d, h_nxt);
        float* lrow = out + (size_t)s*BN*KYV;
        logits_kernel<<<KYV/64, 256, 0, stream>>>(h_nxt, ctx, W_lsm, b_lsm, lrow);
        lse_argmax_kernel<<<BN, 256, 0, stream>>>(lrow, lse, tok);
        sub_lse_kernel<<<512, 256, 0, stream>>>(lrow, lse);
    }
}

// Round 2
// 12951.297 us; speedup vs baseline: 1.0297x; 1.0297x over previous
//
#include <hip/hip_runtime.h>
#include <math.h>

// Problem constants
#define TX 64
#define BN 64
#define TY 32
#define EE 256
#define HH 512
#define H3 1536
#define KYV 32000

typedef __attribute__((ext_vector_type(8))) short bf16x8;
typedef __attribute__((ext_vector_type(4))) float f32x4;
typedef __attribute__((ext_vector_type(4))) short s16x4;

__device__ __forceinline__ float4 ldf4(const float* p) { return *(const float4*)p; }
__device__ __forceinline__ float sigf(float x) { return 1.f / (1.f + expf(-x)); }

// round-to-nearest-even fp32 -> bf16 bits
__device__ __forceinline__ short f2bf(float x) {
    unsigned u = __float_as_uint(x);
    unsigned r = (u + 0x7fffu + ((u >> 16) & 1u)) >> 16;
    return (short)r;
}
__device__ __forceinline__ float bf2f(short h) {
    return __uint_as_float(((unsigned)(unsigned short)h) << 16);
}

// ---------------------------------------------------------------------------
// Generic NT GEMM (fp32): C[M x N] = A[M x K] * B[N x K]^T (+bias), optional
// A row gather. Tiles 64x64, K-tile 32. M,N % 64 == 0, K % 32 == 0.
// ---------------------------------------------------------------------------
__global__ __launch_bounds__(256) void gemm_nt_kernel(
    const float* __restrict__ Abase, const int* __restrict__ gather, int lda,
    const float* __restrict__ Bbase, int ldb, int bofs,
    const float* __restrict__ bias, float* __restrict__ C, int ldc, int K)
{
    __shared__ float As[32][68];
    __shared__ float Bs[32][68];
    const int tid = threadIdx.x;
    const int n0 = blockIdx.x * 64;
    const int m0 = blockIdx.y * 64;
    const int tx = tid & 15, ty = tid >> 4;
    const int li = tid >> 2, lk = (tid & 3) * 8;
    float acc[4][4] = {};
    const float* arow = gather ? (Abase + (size_t)gather[m0 + li] * lda)
                               : (Abase + (size_t)(m0 + li) * lda);
    const float* brow = Bbase + (size_t)(n0 + li) * ldb + bofs;
    for (int kt = 0; kt < K; kt += 32) {
        float4 a0 = ldf4(arow + kt + lk);
        float4 a1 = ldf4(arow + kt + lk + 4);
        float4 b0 = ldf4(brow + kt + lk);
        float4 b1 = ldf4(brow + kt + lk + 4);
        __syncthreads();
        As[lk+0][li]=a0.x; As[lk+1][li]=a0.y; As[lk+2][li]=a0.z; As[lk+3][li]=a0.w;
        As[lk+4][li]=a1.x; As[lk+5][li]=a1.y; As[lk+6][li]=a1.z; As[lk+7][li]=a1.w;
        Bs[lk+0][li]=b0.x; Bs[lk+1][li]=b0.y; Bs[lk+2][li]=b0.z; Bs[lk+3][li]=b0.w;
        Bs[lk+4][li]=b1.x; Bs[lk+5][li]=b1.y; Bs[lk+6][li]=b1.z; Bs[lk+7][li]=b1.w;
        __syncthreads();
        #pragma unroll
        for (int k = 0; k < 32; ++k) {
            float4 av = *(const float4*)&As[k][ty*4];
            float4 bv = *(const float4*)&Bs[k][tx*4];
            acc[0][0] += av.x*bv.x; acc[0][1] += av.x*bv.y; acc[0][2] += av.x*bv.z; acc[0][3] += av.x*bv.w;
            acc[1][0] += av.y*bv.x; acc[1][1] += av.y*bv.y; acc[1][2] += av.y*bv.z; acc[1][3] += av.y*bv.w;
            acc[2][0] += av.z*bv.x; acc[2][1] += av.z*bv.y; acc[2][2] += av.z*bv.z; acc[2][3] += av.z*bv.w;
            acc[3][0] += av.w*bv.x; acc[3][1] += av.w*bv.y; acc[3][2] += av.w*bv.z; acc[3][3] += av.w*bv.w;
        }
    }
    #pragma unroll
    for (int ii = 0; ii < 4; ++ii) {
        int r = m0 + ty*4 + ii;
        #pragma unroll
        for (int jj = 0; jj < 4; ++jj) {
            int c = n0 + tx*4 + jj;
            float v = acc[ii][jj];
            if (bias) v += bias[c];
            C[(size_t)r*ldc + c] = v;
        }
    }
}

// ---------------------------------------------------------------------------
// Split fp32 W into bf16 hi/lo planes (once per launch).
// ---------------------------------------------------------------------------
__global__ __launch_bounds__(256) void wsplit_kernel(
    const float* __restrict__ W, short* __restrict__ hi, short* __restrict__ lo,
    long n4)
{
    for (long i = (long)blockIdx.x*blockDim.x + threadIdx.x; i < n4;
         i += (long)gridDim.x*blockDim.x) {
        float4 v = ((const float4*)W)[i];
        s16x4 h, l;
        h.x = f2bf(v.x); l.x = f2bf(v.x - bf2f(h.x));
        h.y = f2bf(v.y); l.y = f2bf(v.y - bf2f(h.y));
        h.z = f2bf(v.z); l.z = f2bf(v.z - bf2f(h.z));
        h.w = f2bf(v.w); l.w = f2bf(v.w - bf2f(h.w));
        ((s16x4*)hi)[i] = h;
        ((s16x4*)lo)[i] = l;
    }
}

// ---------------------------------------------------------------------------
// Encoder recurrent step (unchanged from round 1).
// ---------------------------------------------------------------------------
__global__ __launch_bounds__(256) void enc_step_kernel(
    const float* __restrict__ GI_f, const float* __restrict__ GI_b,
    const float* __restrict__ Whh_f, const float* __restrict__ bhh_f,
    const float* __restrict__ Whh_b, const float* __restrict__ bhh_b,
    const float* __restrict__ hf_in, float* __restrict__ hf_out,
    const float* __restrict__ hb_in, float* __restrict__ hb_out,
    float* __restrict__ enc_out, int t)
{
    const int blk = blockIdx.x;
    const int dir = blk >> 7;
    const int r = blk & 127;
    const int cg = r >> 1;
    const int bh = r & 1;
    const int sub = threadIdx.x >> 5;
    const int b = bh*32 + (threadIdx.x & 31);
    const int col = cg*8 + sub;

    const float* GI = dir ? GI_b : GI_f;
    const float* W  = dir ? Whh_b : Whh_f;
    const float* bh_v = dir ? bhh_b : bhh_f;
    const float* hin  = dir ? hb_in : hf_in;
    float* hout = dir ? hb_out : hf_out;
    const int tstep = dir ? (TX-1-t) : t;

    const float* hrow = hin + b*HH;
    const float* wr = W + (size_t)col*HH;
    const float* wz = W + (size_t)(HH + col)*HH;
    const float* wn = W + (size_t)(2*HH + col)*HH;
    float ar = 0.f, az = 0.f, an = 0.f;
    for (int k = 0; k < HH; k += 4) {
        float4 hv = ldf4(hrow + k);
        float4 A = ldf4(wr + k), Z = ldf4(wz + k), N = ldf4(wn + k);
        ar += hv.x*A.x + hv.y*A.y + hv.z*A.z + hv.w*A.w;
        az += hv.x*Z.x + hv.y*Z.y + hv.z*Z.z + hv.w*Z.w;
        an += hv.x*N.x + hv.y*N.y + hv.z*N.z + hv.w*N.w;
    }
    size_t gbase = ((size_t)tstep*BN + b) * H3;
    float ir = GI[gbase + col];
    float iz = GI[gbase + HH + col];
    float inn = GI[gbase + 2*HH + col];
    float rr = sigf(ir + ar + bh_v[col]);
    float zz = sigf(iz + az + bh_v[HH + col]);
    float nn = tanhf(inn + rr*(an + bh_v[2*HH + col]));
    float hold = hrow[col];
    float h2 = (1.f - zz)*nn + zz*hold;
    hout[b*HH + col] = h2;
    enc_out[((size_t)tstep*BN + b)*(2*HH) + dir*HH + col] = h2;
}

// ---------------------------------------------------------------------------
// Decoder init: hidden = tanh(h_b_final @ W_init.T + b_init); tok = 1
// ---------------------------------------------------------------------------
__global__ __launch_bounds__(256) void dec_init_kernel(
    const float* __restrict__ hbf, const float* __restrict__ Wi,
    const float* __restrict__ bi, float* __restrict__ hdec, int* __restrict__ tok)
{
    const int b = blockIdx.x, tid = threadIdx.x;
    const float* hr = hbf + b*HH;
    for (int n = tid; n < HH; n += 256) {
        float acc = bi[n];
        const float* w = Wi + (size_t)n*HH;
        for (int k = 0; k < HH; k += 4) {
            float4 hv = ldf4(hr + k), wv = ldf4(w + k);
            acc += hv.x*wv.x + hv.y*wv.y + hv.z*wv.z + hv.w*wv.w;
        }
        hdec[b*HH + n] = tanhf(acc);
    }
    if (b == 0 && tid < 64) tok[tid] = 1;
}

// ---------------------------------------------------------------------------
// Attention + context. Also emits bf16 hi/lo of ctx into A[:,512:1536].
// ---------------------------------------------------------------------------
__global__ __launch_bounds__(256) void attn_kernel(
    const float* __restrict__ h, const float* __restrict__ P,
    const float* __restrict__ enc, const float* __restrict__ Wa1,
    const float* __restrict__ ba1, const float* __restrict__ Wa2,
    const float* __restrict__ ba2, float* __restrict__ ctx,
    short* __restrict__ Ahi, short* __restrict__ Alo)
{
    __shared__ float hs[HH];
    __shared__ float qs[HH];
    __shared__ float ss[TX];
    __shared__ float ww[TX];
    const int b = blockIdx.x, tid = threadIdx.x;
    hs[tid] = h[b*HH + tid];
    hs[tid + 256] = h[b*HH + 256 + tid];
    __syncthreads();
    for (int n = tid; n < HH; n += 256) {
        float acc = ba1[n];
        const float* w = Wa1 + (size_t)n*H3;
        for (int k = 0; k < HH; k += 4) {
            float4 wv = ldf4(w + k);
            acc += hs[k]*wv.x + hs[k+1]*wv.y + hs[k+2]*wv.z + hs[k+3]*wv.w;
        }
        qs[n] = acc;
    }
    __syncthreads();
    {
        const int t = tid >> 2, part = tid & 3;
        const float* p = P + ((size_t)t*BN + b)*HH + part*128;
        const float* w2 = Wa2 + part*128;
        const float* q = qs + part*128;
        float acc = 0.f;
        for (int k = 0; k < 128; k += 4) {
            float4 pv = ldf4(p + k), wv = ldf4(w2 + k);
            acc += wv.x*tanhf(q[k+0] + pv.x);
            acc += wv.y*tanhf(q[k+1] + pv.y);
            acc += wv.z*tanhf(q[k+2] + pv.z);
            acc += wv.w*tanhf(q[k+3] + pv.w);
        }
        acc += __shfl_xor(acc, 1);
        acc += __shfl_xor(acc, 2);
        if (part == 0) ss[t] = acc + ba2[0];
    }
    __syncthreads();
    if (tid < 64) {
        float v = ss[tid];
        float m = v;
        for (int off = 32; off; off >>= 1) m = fmaxf(m, __shfl_xor(m, off));
        float e = expf(v - m);
        float sm = e;
        for (int off = 32; off; off >>= 1) sm += __shfl_xor(sm, off);
        ww[tid] = e / sm;
    }
    __syncthreads();
    for (int c = tid; c < 2*HH; c += 256) {
        float acc = 0.f;
        #pragma unroll 4
        for (int t2 = 0; t2 < TX; ++t2)
            acc += ww[t2] * enc[((size_t)t2*BN + b)*(2*HH) + c];
        ctx[b*(2*HH) + c] = acc;
        short hi = f2bf(acc);
        Ahi[(size_t)b*H3 + HH + c] = hi;
        Alo[(size_t)b*H3 + HH + c] = f2bf(acc - bf2f(hi));
    }
}

// ---------------------------------------------------------------------------
// Decoder GRU step. Also emits bf16 hi/lo of h2 into A[:,0:512].
// ---------------------------------------------------------------------------
__global__ __launch_bounds__(256) void dec_gru_kernel(
    const float* __restrict__ demb, const int* __restrict__ tok,
    const float* __restrict__ ctx, const float* __restrict__ h,
    const float* __restrict__ Wih, const float* __restrict__ Whh,
    const float* __restrict__ bih, const float* __restrict__ bhh,
    float* __restrict__ hout, short* __restrict__ Ahi, short* __restrict__ Alo)
{
    const int col = blockIdx.x*4 + (threadIdx.x >> 6);
    const int b = threadIdx.x & 63;
    const float* emb = demb + (size_t)tok[b]*EE;
    const float* cr = ctx + b*(2*HH);
    const float* hr = h + b*HH;
    const float* wri = Wih + (size_t)col*1280;
    const float* wzi = Wih + (size_t)(HH + col)*1280;
    const float* wni = Wih + (size_t)(2*HH + col)*1280;
    float ir = 0.f, iz = 0.f, inn = 0.f;
    for (int k = 0; k < EE; k += 4) {
        float4 e = ldf4(emb + k);
        float4 A = ldf4(wri + k), Z = ldf4(wzi + k), N = ldf4(wni + k);
        ir  += e.x*A.x + e.y*A.y + e.z*A.z + e.w*A.w;
        iz  += e.x*Z.x + e.y*Z.y + e.z*Z.z + e.w*Z.w;
        inn += e.x*N.x + e.y*N.y + e.z*N.z + e.w*N.w;
    }
    for (int k = 0; k < 2*HH; k += 4) {
        float4 c = ldf4(cr + k);
        float4 A = ldf4(wri + EE + k), Z = ldf4(wzi + EE + k), N = ldf4(wni + EE + k);
        ir  += c.x*A.x + c.y*A.y + c.z*A.z + c.w*A.w;
        iz  += c.x*Z.x + c.y*Z.y + c.z*Z.z + c.w*Z.w;
        inn += c.x*N.x + c.y*N.y + c.z*N.z + c.w*N.w;
    }
    const float* wrh = Whh + (size_t)col*HH;
    const float* wzh = Whh + (size_t)(HH + col)*HH;
    const float* wnh = Whh + (size_t)(2*HH + col)*HH;
    float hrr = 0.f, hzz = 0.f, hnn = 0.f;
    for (int k = 0; k < HH; k += 4) {
        float4 hv = ldf4(hr + k);
        float4 A = ldf4(wrh + k), Z = ldf4(wzh + k), N = ldf4(wnh + k);
        hrr += hv.x*A.x + hv.y*A.y + hv.z*A.z + hv.w*A.w;
        hzz += hv.x*Z.x + hv.y*Z.y + hv.z*Z.z + hv.w*Z.w;
        hnn += hv.x*N.x + hv.y*N.y + hv.z*N.z + hv.w*N.w;
    }
    float rr = sigf(ir + bih[col] + hrr + bhh[col]);
    float zz = sigf(iz + bih[HH + col] + hzz + bhh[HH + col]);
    float nn = tanhf(inn + bih[2*HH + col] + rr*(hnn + bhh[2*HH + col]));
    float hv0 = hr[col];
    float h2 = (1.f - zz)*nn + zz*hv0;
    hout[b*HH + col] = h2;
    short hi = f2bf(h2);
    Ahi[(size_t)b*H3 + col] = hi;
    Alo[(size_t)b*H3 + col] = f2bf(h2 - bf2f(hi));
}

// ---------------------------------------------------------------------------
// MFMA logits: out[b,n] = A[b,:] . W[n,:] + blsm[n], bf16x3 split precision.
// A,W row-major K=1536 in bf16 hi/lo planes. Block = 4 waves; wave w handles
// rows [16w,16w+16); block covers 64 N-cols. Grid = 500.
// MFMA 16x16x32: A frag A[m=lane&15][k=(lane>>4)*8+j]; B frag
// B[n=lane&15][k=(lane>>4)*8+j]; D: row=(lane>>4)*4+reg, col=lane&15.
// ---------------------------------------------------------------------------
__global__ __launch_bounds__(256) void logits_mfma_kernel(
    const short* __restrict__ Ahi, const short* __restrict__ Alo,
    const short* __restrict__ Whi, const short* __restrict__ Wlo,
    const float* __restrict__ blsm, float* __restrict__ outrow)
{
    const int wave = threadIdx.x >> 6;
    const int lane = threadIdx.x & 63;
    const int n0 = blockIdx.x * 64;
    const int m = lane & 15;
    const int q = lane >> 4;

    const short* arow_h = Ahi + (size_t)(wave*16 + m)*H3 + q*8;
    const short* arow_l = Alo + (size_t)(wave*16 + m)*H3 + q*8;
    const short* br0h = Whi + (size_t)(n0 + m)*H3 + q*8;
    const short* br0l = Wlo + (size_t)(n0 + m)*H3 + q*8;

    f32x4 acc0 = {0,0,0,0}, acc1 = {0,0,0,0}, acc2 = {0,0,0,0}, acc3 = {0,0,0,0};
    for (int kt = 0; kt < H3; kt += 32) {
        bf16x8 ah = *(const bf16x8*)(arow_h + kt);
        bf16x8 al = *(const bf16x8*)(arow_l + kt);
        bf16x8 b0h = *(const bf16x8*)(br0h + kt);
        bf16x8 b0l = *(const bf16x8*)(br0l + kt);
        bf16x8 b1h = *(const bf16x8*)(br0h + 16*H3 + kt);
        bf16x8 b1l = *(const bf16x8*)(br0l + 16*H3 + kt);
        bf16x8 b2h = *(const bf16x8*)(br0h + 32*H3 + kt);
        bf16x8 b2l = *(const bf16x8*)(br0l + 32*H3 + kt);
        bf16x8 b3h = *(const bf16x8*)(br0h + 48*H3 + kt);
        bf16x8 b3l = *(const bf16x8*)(br0l + 48*H3 + kt);
        acc0 = __builtin_amdgcn_mfma_f32_16x16x32_bf16(ah, b0h, acc0, 0, 0, 0);
        acc0 = __builtin_amdgcn_mfma_f32_16x16x32_bf16(al, b0h, acc0, 0, 0, 0);
        acc0 = __builtin_amdgcn_mfma_f32_16x16x32_bf16(ah, b0l, acc0, 0, 0, 0);
        acc1 = __builtin_amdgcn_mfma_f32_16x16x32_bf16(ah, b1h, acc1, 0, 0, 0);
        acc1 = __builtin_amdgcn_mfma_f32_16x16x32_bf16(al, b1h, acc1, 0, 0, 0);
        acc1 = __builtin_amdgcn_mfma_f32_16x16x32_bf16(ah, b1l, acc1, 0, 0, 0);
        acc2 = __builtin_amdgcn_mfma_f32_16x16x32_bf16(ah, b2h, acc2, 0, 0, 0);
        acc2 = __builtin_amdgcn_mfma_f32_16x16x32_bf16(al, b2h, acc2, 0, 0, 0);
        acc2 = __builtin_amdgcn_mfma_f32_16x16x32_bf16(ah, b2l, acc2, 0, 0, 0);
        acc3 = __builtin_amdgcn_mfma_f32_16x16x32_bf16(ah, b3h, acc3, 0, 0, 0);
        acc3 = __builtin_amdgcn_mfma_f32_16x16x32_bf16(al, b3h, acc3, 0, 0, 0);
        acc3 = __builtin_amdgcn_mfma_f32_16x16x32_bf16(ah, b3l, acc3, 0, 0, 0);
    }
    const int row = wave*16 + q*4;
    #pragma unroll
    for (int r = 0; r < 4; ++r) {
        size_t ro = (size_t)(row + r)*KYV;
        outrow[ro + n0 +  0 + m] = acc0[r] + blsm[n0 +  0 + m];
        outrow[ro + n0 + 16 + m] = acc1[r] + blsm[n0 + 16 + m];
        outrow[ro + n0 + 32 + m] = acc2[r] + blsm[n0 + 32 + m];
        outrow[ro + n0 + 48 + m] = acc3[r] + blsm[n0 + 48 + m];
    }
}

// ---------------------------------------------------------------------------
// Fallback fp32 logits (used only if ws_size too small for bf16 W planes).
// ---------------------------------------------------------------------------
__global__ __launch_bounds__(256) void logits_kernel(
    const float* __restrict__ h2, const float* __restrict__ ctx,
    const float* __restrict__ Wlsm, const float* __restrict__ blsm,
    float* __restrict__ outrow)
{
    __shared__ float As[32][68];
    __shared__ float Bs[32][68];
    const int tid = threadIdx.x;
    const int n0 = blockIdx.x * 64;
    const int tx = tid & 15, ty = tid >> 4;
    const int li = tid >> 2, lk = (tid & 3) * 8;
    float acc[4][4] = {};
    const float* arow_h = h2 + (size_t)li*HH;
    const float* arow_c = ctx + (size_t)li*(2*HH) - HH;
    const float* brow = Wlsm + (size_t)(n0 + li)*H3;
    for (int kt = 0; kt < H3; kt += 32) {
        const float* src = ((kt + lk) < HH) ? arow_h : arow_c;
        float4 a0 = ldf4(src + kt + lk);
        float4 a1 = ldf4(src + kt + lk + 4);
        float4 b0 = ldf4(brow + kt + lk);
        float4 b1 = ldf4(brow + kt + lk + 4);
        __syncthreads();
        As[lk+0][li]=a0.x; As[lk+1][li]=a0.y; As[lk+2][li]=a0.z; As[lk+3][li]=a0.w;
        As[lk+4][li]=a1.x; As[lk+5][li]=a1.y; As[lk+6][li]=a1.z; As[lk+7][li]=a1.w;
        Bs[lk+0][li]=b0.x; Bs[lk+1][li]=b0.y; Bs[lk+2][li]=b0.z; Bs[lk+3][li]=b0.w;
        Bs[lk+4][li]=b1.x; Bs[lk+5][li]=b1.y; Bs[lk+6][li]=b1.z; Bs[lk+7][li]=b1.w;
        __syncthreads();
        #pragma unroll
        for (int k = 0; k < 32; ++k) {
            float4 av = *(const float4*)&As[k][ty*4];
            float4 bv = *(const float4*)&Bs[k][tx*4];
            acc[0][0] += av.x*bv.x; acc[0][1] += av.x*bv.y; acc[0][2] += av.x*bv.z; acc[0][3] += av.x*bv.w;
            acc[1][0] += av.y*bv.x; acc[1][1] += av.y*bv.y; acc[1][2] += av.y*bv.z; acc[1][3] += av.y*bv.w;
            acc[2][0] += av.z*bv.x; acc[2][1] += av.z*bv.y; acc[2][2] += av.z*bv.z; acc[2][3] += av.z*bv.w;
            acc[3][0] += av.w*bv.x; acc[3][1] += av.w*bv.y; acc[3][2] += av.w*bv.z; acc[3][3] += av.w*bv.w;
        }
    }
    #pragma unroll
    for (int ii = 0; ii < 4; ++ii) {
        int r = ty*4 + ii;
        #pragma unroll
        for (int jj = 0; jj < 4; ++jj) {
            int c = n0 + tx*4 + jj;
            outrow[(size_t)r*KYV + c] = acc[ii][jj] + blsm[c];
        }
    }
}

// ---------------------------------------------------------------------------
// Per-row logsumexp + argmax over 32000 logits (float4 loads). 1 block/row.
// ---------------------------------------------------------------------------
__global__ __launch_bounds__(256) void lse_argmax_kernel(
    const float* __restrict__ rows, float* __restrict__ lse, int* __restrict__ tok)
{
    const int b = blockIdx.x, tid = threadIdx.x;
    const float4* row4 = (const float4*)(rows + (size_t)b*KYV);
    float m = -1e30f, s = 0.f; int bi = 0;
    for (int i = tid; i < KYV/4; i += 256) {
        float4 v = row4[i];
        if (v.x > m) { s = s*expf(m - v.x) + 1.f; m = v.x; bi = 4*i+0; } else s += expf(v.x - m);
        if (v.y > m) { s = s*expf(m - v.y) + 1.f; m = v.y; bi = 4*i+1; } else s += expf(v.y - m);
        if (v.z > m) { s = s*expf(m - v.z) + 1.f; m = v.z; bi = 4*i+2; } else s += expf(v.z - m);
        if (v.w > m) { s = s*expf(m - v.w) + 1.f; m = v.w; bi = 4*i+3; } else s += expf(v.w - m);
    }
    for (int off = 32; off; off >>= 1) {
        float m2 = __shfl_xor(m, off);
        float s2 = __shfl_xor(s, off);
        int i2 = __shfl_xor(bi, off);
        if (m2 > m || (m2 == m && i2 < bi)) { s = s2 + s*expf(m - m2); m = m2; bi = i2; }
        else s = s + s2*expf(m2 - m);
    }
    __shared__ float ms[4], ssh[4];
    __shared__ int is_[4];
    const int wid = tid >> 6;
    if ((tid & 63) == 0) { ms[wid] = m; ssh[wid] = s; is_[wid] = bi; }
    __syncthreads();
    if (tid == 0) {
        for (int w = 1; w < 4; ++w) {
            float m2 = ms[w], s2 = ssh[w]; int i2 = is_[w];
            if (m2 > m || (m2 == m && i2 < bi)) { s = s2 + s*expf(m - m2); m = m2; bi = i2; }
            else s = s + s2*expf(m2 - m);
        }
        lse[b] = m + logf(s);
        tok[b] = bi;
    }
}

// out = logits - lse[row], in-place, float4.
__global__ __launch_bounds__(256) void sub_lse_kernel(
    float* __restrict__ rows, const float* __restrict__ lse)
{
    const size_t total4 = (size_t)BN * KYV / 4;
    for (size_t i = blockIdx.x*blockDim.x + threadIdx.x; i < total4;
         i += (size_t)gridDim.x*blockDim.x) {
        float4 v = ((float4*)rows)[i];
        float l = lse[(i*4) / KYV];
        v.x -= l; v.y -= l; v.z -= l; v.w -= l;
        ((float4*)rows)[i] = v;
    }
}

// ---------------------------------------------------------------------------
extern "C" void kernel_launch(void* const* d_in, const int* in_sizes, int n_in,
                              void* d_out, int out_size, void* d_ws, size_t ws_size,
                              hipStream_t stream)
{
    const int*   inputs  = (const int*)  d_in[0];
    const float* enc_emb = (const float*)d_in[2];
    const float* W_ih_f  = (const float*)d_in[3];
    const float* W_hh_f  = (const float*)d_in[4];
    const float* b_ih_f  = (const float*)d_in[5];
    const float* b_hh_f  = (const float*)d_in[6];
    const float* W_ih_b  = (const float*)d_in[7];
    const float* W_hh_b  = (const float*)d_in[8];
    const float* b_ih_b  = (const float*)d_in[9];
    const float* b_hh_b  = (const float*)d_in[10];
    const float* W_init  = (const float*)d_in[11];
    const float* b_init  = (const float*)d_in[12];
    const float* dec_emb = (const float*)d_in[13];
    const float* W_ih_d  = (const float*)d_in[14];
    const float* W_hh_d  = (const float*)d_in[15];
    const float* b_ih_d  = (const float*)d_in[16];
    const float* b_hh_d  = (const float*)d_in[17];
    const float* W_lsm   = (const float*)d_in[18];
    const float* b_lsm   = (const float*)d_in[19];
    const float* W_a1    = (const float*)d_in[20];
    const float* b_a1    = (const float*)d_in[21];
    const float* W_a2    = (const float*)d_in[22];
    const float* b_a2    = (const float*)d_in[23];

    float* ws = (float*)d_ws;
    float* GI_f   = ws;
    float* GI_b   = GI_f + (size_t)4096*1536;
    float* enc_out= GI_b + (size_t)4096*1536;
    float* P_enc  = enc_out + (size_t)4096*1024;
    float* hf     = P_enc + (size_t)4096*512;
    float* hb     = hf + 2*BN*HH;
    float* hdec   = hb + 2*BN*HH;
    float* ctx    = hdec + 2*BN*HH;
    float* lse    = ctx + BN*2*HH;
    int*   tok    = (int*)(lse + BN);
    // bf16 region (16B aligned by construction: all offsets above are even)
    short* A_hi = (short*)(tok + 64);
    short* A_lo = A_hi + (size_t)BN*H3;
    short* W_hi = A_lo + (size_t)BN*H3;
    short* W_lo = W_hi + (size_t)KYV*H3;
    size_t need_bytes = (size_t)((char*)(W_lo + (size_t)KYV*H3) - (char*)d_ws);
    const bool use_mfma = (ws_size >= need_bytes);

    hipMemsetAsync(hf, 0, BN*HH*sizeof(float), stream);
    hipMemsetAsync(hb, 0, BN*HH*sizeof(float), stream);

    if (use_mfma) {
        wsplit_kernel<<<2048, 256, 0, stream>>>(W_lsm, W_hi, W_lo,
                                                (long)KYV*H3/4);
    }

    // Input projections for both encoder directions
    dim3 g1(H3/64, (TX*BN)/64);
    gemm_nt_kernel<<<g1, 256, 0, stream>>>(enc_emb, inputs, EE, W_ih_f, EE, 0,
                                           b_ih_f, GI_f, H3, EE);
    gemm_nt_kernel<<<g1, 256, 0, stream>>>(enc_emb, inputs, EE, W_ih_b, EE, 0,
                                           b_ih_b, GI_b, H3, EE);

    for (int t = 0; t < TX; ++t) {
        const float* hfi = hf + (t & 1)*BN*HH;
        float*       hfo = hf + ((t + 1) & 1)*BN*HH;
        const float* hbi = hb + (t & 1)*BN*HH;
        float*       hbo = hb + ((t + 1) & 1)*BN*HH;
        enc_step_kernel<<<256, 256, 0, stream>>>(GI_f, GI_b, W_hh_f, b_hh_f,
                                                 W_hh_b, b_hh_b, hfi, hfo, hbi, hbo,
                                                 enc_out, t);
    }

    dim3 g2(HH/64, (TX*BN)/64);
    gemm_nt_kernel<<<g2, 256, 0, stream>>>(enc_out, nullptr, 2*HH, W_a1, H3, HH,
                                           nullptr, P_enc, HH, 2*HH);

    dec_init_kernel<<<BN, 256, 0, stream>>>(hb, W_init, b_init, hdec, tok);

    float* out = (float*)d_out;
    for (int s = 0; s < TY; ++s) {
        float* h_cur = hdec + (s & 1)*BN*HH;
        float* h_nxt = hdec + ((s + 1) & 1)*BN*HH;
        attn_kernel<<<BN, 256, 0, stream>>>(h_cur, P_enc, enc_out, W_a1, b_a1,
                                            W_a2, b_a2, ctx, A_hi, A_lo);
        dec_gru_kernel<<<128, 256, 0, stream>>>(dec_emb, tok, ctx, h_cur,
                                                W_ih_d, W_hh_d, b_ih_d, b_hh_d,
                                                h_nxt, A_hi, A_lo);
        float* lrow = out + (size_t)s*BN*KYV;
        if (use_mfma) {
            logits_mfma_kernel<<<KYV/64, 256, 0, stream>>>(A_hi, A_lo, W_hi, W_lo,
                                                           b_lsm, lrow);
        } else {
            logits_kernel<<<KYV/64, 256, 0, stream>>>(h_nxt, ctx, W_lsm, b_lsm, lrow);
        }
        lse_argmax_kernel<<<BN, 256, 0, stream>>>(lrow, lse, tok);
        sub_lse_kernel<<<512, 256, 0, stream>>>(lrow, lse);
    }
}